// Round 9
// baseline (100.925 us; speedup 1.0000x reference)
//
#include <hip/hip_runtime.h>

constexpr int NBINS = 256;
constexpr int HPI = 3 * NBINS;  // 768 bins per image (3 channels)
constexpr int BPI = 24;         // blocks per image: 64*24=1536 = exactly 6 blocks/CU

typedef int iv4 __attribute__((ext_vector_type(4)));

// ---------------- Kernel 1: partial histograms + packed uint8 copy ----------------
// Input is read exactly once (nt-loads: keep it OUT of L2/L3 so the 50 MB
// packed copy stays LLC-resident for the apply kernel). Element index of v.x
// is 4*i; (4*i) % 3 == i % 3; stride % 3 == 0 keeps channel phase invariant.
__global__ __launch_bounds__(256)
void hist_part_kernel(const iv4* __restrict__ in, int* __restrict__ part,
                      unsigned* __restrict__ packed, int n4_per_img) {
    __shared__ int subh[4][HPI];  // per-wave sub-histograms, 12 KB
    const int tid = threadIdx.x;
    const int wave = tid >> 6;

    for (int i = tid; i < 4 * HPI; i += 256) ((int*)subh)[i] = 0;
    __syncthreads();

    const int img = blockIdx.x / BPI;
    const int blk = blockIdx.x % BPI;
    const size_t ibase = (size_t)img * n4_per_img;
    const iv4* p = in + ibase;
    unsigned* pk = packed + ibase;
    const int stride = BPI * 256;  // 6144, divisible by 3

    int i = blk * 256 + tid;
    int c0 = i % 3;
    int c1 = c0 + 1; if (c1 == 3) c1 = 0;
    int c2 = c1 + 1; if (c2 == 3) c2 = 0;
    int c3 = c2 + 1; if (c3 == 3) c3 = 0;
    const int b0 = c0 * NBINS, b1 = c1 * NBINS, b2 = c2 * NBINS, b3 = c3 * NBINS;

    for (; i + stride < n4_per_img; i += 2 * stride) {
        iv4 v0 = __builtin_nontemporal_load(&p[i]);            // single-use: bypass caches
        iv4 v1 = __builtin_nontemporal_load(&p[i + stride]);
        pk[i]          = (unsigned)(v0.x & 255) | ((unsigned)(v0.y & 255) << 8) |
                         ((unsigned)(v0.z & 255) << 16) | ((unsigned)(v0.w & 255) << 24);
        pk[i + stride] = (unsigned)(v1.x & 255) | ((unsigned)(v1.y & 255) << 8) |
                         ((unsigned)(v1.z & 255) << 16) | ((unsigned)(v1.w & 255) << 24);
        atomicAdd(&subh[wave][b0 + (v0.x & 255)], 1);
        atomicAdd(&subh[wave][b1 + (v0.y & 255)], 1);
        atomicAdd(&subh[wave][b2 + (v0.z & 255)], 1);
        atomicAdd(&subh[wave][b3 + (v0.w & 255)], 1);
        atomicAdd(&subh[wave][b0 + (v1.x & 255)], 1);
        atomicAdd(&subh[wave][b1 + (v1.y & 255)], 1);
        atomicAdd(&subh[wave][b2 + (v1.z & 255)], 1);
        atomicAdd(&subh[wave][b3 + (v1.w & 255)], 1);
    }
    if (i < n4_per_img) {
        iv4 v = __builtin_nontemporal_load(&p[i]);
        pk[i] = (unsigned)(v.x & 255) | ((unsigned)(v.y & 255) << 8) |
                ((unsigned)(v.z & 255) << 16) | ((unsigned)(v.w & 255) << 24);
        atomicAdd(&subh[wave][b0 + (v.x & 255)], 1);
        atomicAdd(&subh[wave][b1 + (v.y & 255)], 1);
        atomicAdd(&subh[wave][b2 + (v.z & 255)], 1);
        atomicAdd(&subh[wave][b3 + (v.w & 255)], 1);
    }
    __syncthreads();

    int* gp = part + (size_t)blockIdx.x * HPI;  // own slot: plain store, no atomics
    for (int e = tid; e < HPI; e += 256)
        gp[e] = subh[0][e] + subh[1][e] + subh[2][e] + subh[3][e];
}

// ---------------- Kernel 2: fused LUT build + apply ----------------
// Each block redundantly reduces its image's 24 partials (L2/L3-resident) and
// builds the 3-channel LUT in LDS, then applies to its chunk of the packed
// copy. Kernel boundary provides hist->here coherence.
__global__ __launch_bounds__(256)
void lut_apply_kernel(const unsigned* __restrict__ packed, iv4* __restrict__ out,
                      const int* __restrict__ part, int n4_per_img) {
    __shared__ int cum[NBINS];
    __shared__ int lutS[HPI];
    __shared__ int lastNZ;

    const int tid = threadIdx.x;
    const int img = blockIdx.x / BPI;
    const int blk = blockIdx.x % BPI;

    // ---- Reduce 24 partials for the 3 channels (coalesced, ~73 KB from LLC) ----
    const int* pp = part + (size_t)img * BPI * HPI;
    int h[3];
    #pragma unroll
    for (int ch = 0; ch < 3; ++ch) {
        int s = 0;
        #pragma unroll 4
        for (int b = 0; b < BPI; ++b) s += pp[b * HPI + ch * NBINS + tid];
        h[ch] = s;
    }

    // ---- Build LUT per channel (reference semantics) ----
    #pragma unroll
    for (int ch = 0; ch < 3; ++ch) {
        if (tid == 0) lastNZ = 0;
        cum[tid] = h[ch];
        __syncthreads();
        if (h[ch] > 0) atomicMax(&lastNZ, tid);

        for (int off = 1; off < NBINS; off <<= 1) {
            int add = (tid >= off) ? cum[tid - off] : 0;
            __syncthreads();
            cum[tid] += add;
            __syncthreads();
        }

        const int sum  = cum[NBINS - 1];
        const int last = lastNZ;
        const int hl   = cum[last] - (last > 0 ? cum[last - 1] : 0);  // histo[last]
        const int step = (sum - hl) / 255;

        int v;
        if (step == 0) {
            v = tid;  // reference: where(step==0, img, ...)
        } else {
            // lut = clip(concat([0], (cumsum+step//2)//step [:-1]), 0, 255)
            const int cp = (tid == 0) ? 0 : cum[tid - 1];
            v = (cp + (step >> 1)) / step;
            if (v > 255) v = 255;
        }
        lutS[ch * NBINS + tid] = v;
        __syncthreads();  // cum/lastNZ reused next channel
    }

    // ---- Apply: packed uint8 in (LLC-hit), nt-int4 out ----
    const size_t ibase = (size_t)img * n4_per_img;
    const unsigned* pk = packed + ibase;
    iv4* q = out + ibase;
    const int stride = BPI * 256;  // divisible by 3

    int i = blk * 256 + tid;
    int c0 = i % 3;
    int c1 = c0 + 1; if (c1 == 3) c1 = 0;
    int c2 = c1 + 1; if (c2 == 3) c2 = 0;
    int c3 = c2 + 1; if (c3 == 3) c3 = 0;
    const int b0 = c0 * NBINS, b1 = c1 * NBINS, b2 = c2 * NBINS, b3 = c3 * NBINS;

    for (; i + stride < n4_per_img; i += 2 * stride) {
        unsigned w0 = pk[i];
        unsigned w1 = pk[i + stride];
        iv4 o0, o1;
        o0.x = lutS[b0 + (w0 & 255)];
        o0.y = lutS[b1 + ((w0 >> 8) & 255)];
        o0.z = lutS[b2 + ((w0 >> 16) & 255)];
        o0.w = lutS[b3 + (w0 >> 24)];
        o1.x = lutS[b0 + (w1 & 255)];
        o1.y = lutS[b1 + ((w1 >> 8) & 255)];
        o1.z = lutS[b2 + ((w1 >> 16) & 255)];
        o1.w = lutS[b3 + (w1 >> 24)];
        __builtin_nontemporal_store(o0, &q[i]);           // output never re-read:
        __builtin_nontemporal_store(o1, &q[i + stride]);  // don't pollute LLC
    }
    if (i < n4_per_img) {
        unsigned w = pk[i];
        iv4 o;
        o.x = lutS[b0 + (w & 255)];
        o.y = lutS[b1 + ((w >> 8) & 255)];
        o.z = lutS[b2 + ((w >> 16) & 255)];
        o.w = lutS[b3 + (w >> 24)];
        __builtin_nontemporal_store(o, &q[i]);
    }
}

extern "C" void kernel_launch(void* const* d_in, const int* in_sizes, int n_in,
                              void* d_out, int out_size, void* d_ws, size_t ws_size,
                              hipStream_t stream) {
    const int* in = (const int*)d_in[0];
    int* out = (int*)d_out;

    const int npix = 512 * 512;
    const int ints_per_img = 3 * npix;
    const int n4_per_img = ints_per_img / 4;        // 196608 (= 32 * 6144 exactly)
    const int n_img = in_sizes[0] / ints_per_img;   // 64

    // ws layout: partials (4.7 MB) | packed image copy (50 MB). No zero-init
    // needed: every partial slot is unconditionally written each call.
    int* part = (int*)d_ws;
    unsigned* packed = (unsigned*)(part + (size_t)n_img * BPI * HPI);

    hist_part_kernel<<<n_img * BPI, 256, 0, stream>>>((const iv4*)in, part, packed, n4_per_img);
    lut_apply_kernel<<<n_img * BPI, 256, 0, stream>>>(packed, (iv4*)out, part, n4_per_img);
}

// Round 10
// 87.255 us; speedup vs baseline: 1.1567x; 1.1567x over previous
//
#include <hip/hip_runtime.h>

constexpr int NBINS = 256;
constexpr int HPI = 3 * NBINS;  // 768 bins per image (3 channels)
constexpr int BPI = 24;         // blocks per image: 64*24=1536 = exactly 6 blocks/CU

typedef int iv4 __attribute__((ext_vector_type(4)));

// ---------------- Kernel 1: partial histograms + packed uint8 copy ----------------
// NORMAL input loads (round-9 lesson: graph-replay steady state keeps the
// input LLC-resident across calls; nt-loads forfeit that). Element index of
// v.x is 4*i; (4*i)%3 == i%3; stride%3==0 keeps channel phase invariant.
__global__ __launch_bounds__(256)
void hist_part_kernel(const iv4* __restrict__ in, int* __restrict__ part,
                      unsigned* __restrict__ packed, int n4_per_img) {
    __shared__ int subh[4][HPI];  // per-wave sub-histograms, 12 KB
    const int tid = threadIdx.x;
    const int wave = tid >> 6;

    for (int i = tid; i < 4 * HPI; i += 256) ((int*)subh)[i] = 0;
    __syncthreads();

    const int img = blockIdx.x / BPI;
    const int blk = blockIdx.x % BPI;
    const size_t ibase = (size_t)img * n4_per_img;
    const iv4* p = in + ibase;
    unsigned* pk = packed + ibase;
    const int stride = BPI * 256;  // 6144, divisible by 3

    int i = blk * 256 + tid;
    int c0 = i % 3;
    int c1 = c0 + 1; if (c1 == 3) c1 = 0;
    int c2 = c1 + 1; if (c2 == 3) c2 = 0;
    int c3 = c2 + 1; if (c3 == 3) c3 = 0;
    const int b0 = c0 * NBINS, b1 = c1 * NBINS, b2 = c2 * NBINS, b3 = c3 * NBINS;

    for (; i + stride < n4_per_img; i += 2 * stride) {
        iv4 v0 = p[i];
        iv4 v1 = p[i + stride];
        pk[i]          = (unsigned)(v0.x & 255) | ((unsigned)(v0.y & 255) << 8) |
                         ((unsigned)(v0.z & 255) << 16) | ((unsigned)(v0.w & 255) << 24);
        pk[i + stride] = (unsigned)(v1.x & 255) | ((unsigned)(v1.y & 255) << 8) |
                         ((unsigned)(v1.z & 255) << 16) | ((unsigned)(v1.w & 255) << 24);
        atomicAdd(&subh[wave][b0 + (v0.x & 255)], 1);
        atomicAdd(&subh[wave][b1 + (v0.y & 255)], 1);
        atomicAdd(&subh[wave][b2 + (v0.z & 255)], 1);
        atomicAdd(&subh[wave][b3 + (v0.w & 255)], 1);
        atomicAdd(&subh[wave][b0 + (v1.x & 255)], 1);
        atomicAdd(&subh[wave][b1 + (v1.y & 255)], 1);
        atomicAdd(&subh[wave][b2 + (v1.z & 255)], 1);
        atomicAdd(&subh[wave][b3 + (v1.w & 255)], 1);
    }
    if (i < n4_per_img) {
        iv4 v = p[i];
        pk[i] = (unsigned)(v.x & 255) | ((unsigned)(v.y & 255) << 8) |
                ((unsigned)(v.z & 255) << 16) | ((unsigned)(v.w & 255) << 24);
        atomicAdd(&subh[wave][b0 + (v.x & 255)], 1);
        atomicAdd(&subh[wave][b1 + (v.y & 255)], 1);
        atomicAdd(&subh[wave][b2 + (v.z & 255)], 1);
        atomicAdd(&subh[wave][b3 + (v.w & 255)], 1);
    }
    __syncthreads();

    int* gp = part + (size_t)blockIdx.x * HPI;  // own slot: plain store, no atomics
    for (int e = tid; e < HPI; e += 256)
        gp[e] = subh[0][e] + subh[1][e] + subh[2][e] + subh[3][e];
}

// ---------------- Kernel 2: fused LUT build (wave-shfl scan) + apply ----------------
// Scan is barrier-free within a wave: 6 __shfl_up steps; wave totals, global
// last-nonzero and histo[last] go through tiny LDS slots -> 3 barriers per
// channel (vs 48 for Hillis-Steele), so the per-block LUT prelude is ~1-2 us.
__global__ __launch_bounds__(256)
void lut_apply_kernel(const unsigned* __restrict__ packed, iv4* __restrict__ out,
                      const int* __restrict__ part, int n4_per_img) {
    __shared__ int lutS[HPI];
    __shared__ int waveTot[4];
    __shared__ int waveHi[4];   // per-wave highest nonzero bin (-1 if none)
    __shared__ int hlS;         // histo[last]

    const int tid  = threadIdx.x;
    const int wave = tid >> 6;
    const int lane = tid & 63;
    const int img  = blockIdx.x / BPI;
    const int blk  = blockIdx.x % BPI;

    // ---- Reduce 24 partials for 3 channels (coalesced, L2/L3-resident) ----
    const int* pp = part + (size_t)img * BPI * HPI;
    int h[3];
    #pragma unroll
    for (int ch = 0; ch < 3; ++ch) {
        int s = 0;
        #pragma unroll 4
        for (int b = 0; b < BPI; ++b) s += pp[b * HPI + ch * NBINS + tid];
        h[ch] = s;
    }

    // ---- Build LUT per channel ----
    #pragma unroll
    for (int ch = 0; ch < 3; ++ch) {
        const int hv = h[ch];

        // inclusive scan within wave (64 lanes, no barriers)
        int cum = hv;
        #pragma unroll
        for (int d = 1; d < 64; d <<= 1) {
            int v = __shfl_up(cum, d, 64);
            if (lane >= d) cum += v;
        }

        // wave total + per-wave last-nonzero bin
        unsigned long long nzmask = __ballot(hv > 0);
        if (lane == 63) waveTot[wave] = cum;
        if (lane == 0)
            waveHi[wave] = nzmask ? (wave * 64 + 63 - __clzll(nzmask)) : -1;
        __syncthreads();  // barrier 1

        // add totals of preceding waves -> global inclusive cumsum
        int add = 0, sum = 0;
        #pragma unroll
        for (int w = 0; w < 4; ++w) {
            int t = waveTot[w];
            if (w < wave) add += t;
            sum += t;
        }
        cum += add;

        int last = max(max(waveHi[0], waveHi[1]), max(waveHi[2], waveHi[3]));
        if (tid == last) hlS = hv;  // broadcast histo[last]
        __syncthreads();  // barrier 2

        const int step = (sum - hlS) / 255;
        int v;
        if (step == 0) {
            v = tid;  // reference: where(step==0, img, ...)
        } else {
            // exclusive prefix = inclusive - own; lut = clip((cp+step/2)/step, 0, 255)
            const int cp = cum - hv;
            v = (cp + (step >> 1)) / step;
            if (v > 255) v = 255;
        }
        lutS[ch * NBINS + tid] = v;
        __syncthreads();  // barrier 3 (waveTot/waveHi/hlS reused next channel)
    }

    // ---- Apply: packed uint8 in (LLC-hit), nt-int4 out ----
    const size_t ibase = (size_t)img * n4_per_img;
    const unsigned* pk = packed + ibase;
    iv4* q = out + ibase;
    const int stride = BPI * 256;  // divisible by 3

    int i = blk * 256 + tid;
    int c0 = i % 3;
    int c1 = c0 + 1; if (c1 == 3) c1 = 0;
    int c2 = c1 + 1; if (c2 == 3) c2 = 0;
    int c3 = c2 + 1; if (c3 == 3) c3 = 0;
    const int b0 = c0 * NBINS, b1 = c1 * NBINS, b2 = c2 * NBINS, b3 = c3 * NBINS;

    for (; i + stride < n4_per_img; i += 2 * stride) {
        unsigned w0 = pk[i];
        unsigned w1 = pk[i + stride];
        iv4 o0, o1;
        o0.x = lutS[b0 + (w0 & 255)];
        o0.y = lutS[b1 + ((w0 >> 8) & 255)];
        o0.z = lutS[b2 + ((w0 >> 16) & 255)];
        o0.w = lutS[b3 + (w0 >> 24)];
        o1.x = lutS[b0 + (w1 & 255)];
        o1.y = lutS[b1 + ((w1 >> 8) & 255)];
        o1.z = lutS[b2 + ((w1 >> 16) & 255)];
        o1.w = lutS[b3 + (w1 >> 24)];
        __builtin_nontemporal_store(o0, &q[i]);           // output never re-read:
        __builtin_nontemporal_store(o1, &q[i + stride]);  // don't pollute LLC
    }
    if (i < n4_per_img) {
        unsigned w = pk[i];
        iv4 o;
        o.x = lutS[b0 + (w & 255)];
        o.y = lutS[b1 + ((w >> 8) & 255)];
        o.z = lutS[b2 + ((w >> 16) & 255)];
        o.w = lutS[b3 + (w >> 24)];
        __builtin_nontemporal_store(o, &q[i]);
    }
}

extern "C" void kernel_launch(void* const* d_in, const int* in_sizes, int n_in,
                              void* d_out, int out_size, void* d_ws, size_t ws_size,
                              hipStream_t stream) {
    const int* in = (const int*)d_in[0];
    int* out = (int*)d_out;

    const int npix = 512 * 512;
    const int ints_per_img = 3 * npix;
    const int n4_per_img = ints_per_img / 4;        // 196608 (= 32 * 6144 exactly)
    const int n_img = in_sizes[0] / ints_per_img;   // 64

    // ws layout: partials (4.7 MB) | packed image copy (50 MB). No zero-init
    // needed: every partial slot is unconditionally written each call.
    int* part = (int*)d_ws;
    unsigned* packed = (unsigned*)(part + (size_t)n_img * BPI * HPI);

    hist_part_kernel<<<n_img * BPI, 256, 0, stream>>>((const iv4*)in, part, packed, n4_per_img);
    lut_apply_kernel<<<n_img * BPI, 256, 0, stream>>>(packed, (iv4*)out, part, n4_per_img);
}